// Round 10
// baseline (300.624 us; speedup 1.0000x reference)
//
#include <hip/hip_runtime.h>
#include <hip/hip_bf16.h>

#define B_  4
#define L_  2048
#define D_  1024
#define H_  16
#define DH_ 64

typedef unsigned short u16;
typedef __bf16 bf16x8 __attribute__((ext_vector_type(8)));
typedef float  f32x4  __attribute__((ext_vector_type(4)));

union U16x8 { uint4 u; bf16x8 b; u16 s[8]; };

__device__ inline bf16x8 ld_g16(const u16* p) {
  U16x8 c; c.u = *(const uint4*)p; return c.b;
}

__device__ inline u16 f2bf(float f) {
  union { __bf16 h; u16 s; } c; c.h = (__bf16)f; return c.s;
}

__device__ inline unsigned int pk2(float a, float b) {
  return (unsigned int)f2bf(a) | ((unsigned int)f2bf(b) << 16);
}

// async global->LDS, 16B per lane; LDS dest is wave-uniform base (HW adds lane*16)
__device__ inline void gll16(const u16* g, u16* l) {
  __builtin_amdgcn_global_load_lds(
      (const __attribute__((address_space(1))) unsigned int*)g,
      (__attribute__((address_space(3))) unsigned int*)l,
      16, 0, 0);
}

// ---------------------------------------------------------------- conv x -> bf16
__global__ __launch_bounds__(256) void conv_x_kernel(const float* __restrict__ x,
                                                     u16* __restrict__ xb) {
  const int i = blockIdx.x * 256 + threadIdx.x;
  const float4 v = ((const float4*)x)[i];
  ushort4 o;
  o.x = f2bf(v.x); o.y = f2bf(v.y); o.z = f2bf(v.z); o.w = f2bf(v.w);
  ((ushort4*)xb)[i] = o;
}

// ------------------------------------------------- W -> W^T bf16 (LDS transpose)
__global__ __launch_bounds__(256) void conv_wt_kernel(const float* __restrict__ Wq,
                                                      const float* __restrict__ Wk,
                                                      const float* __restrict__ Wv,
                                                      u16* __restrict__ Wt) {
  __shared__ float tile[32][33];
  const int z = blockIdx.z;
  const float* W = (z == 0) ? Wq : ((z == 1) ? Wk : Wv);
  u16* o = Wt + (size_t)z * D_ * D_;
  const int n0 = blockIdx.x * 32, k0 = blockIdx.y * 32;
  const int tx = threadIdx.x, ty = threadIdx.y;  // 32 x 8
#pragma unroll
  for (int i = 0; i < 4; ++i)
    tile[ty + i * 8][tx] = W[(size_t)(k0 + ty + i * 8) * D_ + n0 + tx];
  __syncthreads();
#pragma unroll
  for (int i = 0; i < 4; ++i)
    o[(size_t)(n0 + ty + i * 8) * D_ + k0 + tx] = f2bf(tile[tx][ty + i * 8]);
}

// --------------------------------------------------------------- QKV projection
// C[8192,1024] = xb @ W (+bias), W given transposed (Wt[n][k]). 128x128 tile, BK=64.
// Output HEAD-MAJOR [B,H,L,DH]. Q is pre-scaled by 0.125*log2(e) (folded QK scale).
__global__ __launch_bounds__(256) void qkv_gemm(
    const u16* __restrict__ xb, const u16* __restrict__ Wt,
    const float* __restrict__ bq, const float* __restrict__ bk,
    const float* __restrict__ bv,
    u16* __restrict__ Qo, u16* __restrict__ Ko, u16* __restrict__ Vo) {
  __shared__ u16 As[128 * 64];
  __shared__ u16 Bs[128 * 64];

  const int z = blockIdx.z;
  const u16* W = Wt + (size_t)z * (D_ * D_);
  const float* bias = (z == 0) ? bq : ((z == 1) ? bk : bv);
  u16* out = (z == 0) ? Qo : ((z == 1) ? Ko : Vo);
  const float oscale = (z == 0) ? (0.125f * 1.44269504088896340736f) : 1.0f;

  const int tid = threadIdx.x;
  const int w = tid >> 6, lane = tid & 63;
  const int wr = w >> 1, wc = w & 1;
  const int m0 = blockIdx.x * 128, n0 = blockIdx.y * 128;

  const int srow = lane >> 3;              // 0..7 within the 8-row strip
  const int scg  = (lane & 7) ^ srow;      // pre-swizzled source col-group

  f32x4 acc[4][4];
#pragma unroll
  for (int i = 0; i < 4; ++i)
#pragma unroll
    for (int j = 0; j < 4; ++j) acc[i][j] = f32x4{0.f, 0.f, 0.f, 0.f};

  const int lm = lane & 15, lg = lane >> 4;

  for (int kk = 0; kk < D_ / 64; ++kk) {
    const int k0 = kk * 64;
#pragma unroll
    for (int i = 0; i < 4; ++i) {
      const int rbase = i * 32 + w * 8;
      gll16(xb + (size_t)(m0 + rbase + srow) * D_ + k0 + scg * 8, &As[rbase * 64]);
      gll16(W  + (size_t)(n0 + rbase + srow) * D_ + k0 + scg * 8, &Bs[rbase * 64]);
    }
    __syncthreads();

#pragma unroll
    for (int st = 0; st < 2; ++st) {
      bf16x8 af[4], bfr[4];
#pragma unroll
      for (int mt = 0; mt < 4; ++mt) {
        const int r = wr * 64 + mt * 16 + lm;
        const int cg = (st * 4 + lg) ^ (r & 7);
        U16x8 c; c.u = *(const uint4*)&As[r * 64 + cg * 8];
        af[mt] = c.b;
      }
#pragma unroll
      for (int nt = 0; nt < 4; ++nt) {
        const int r = wc * 64 + nt * 16 + lm;
        const int cg = (st * 4 + lg) ^ (r & 7);
        U16x8 c; c.u = *(const uint4*)&Bs[r * 64 + cg * 8];
        bfr[nt] = c.b;
      }
#pragma unroll
      for (int mt = 0; mt < 4; ++mt)
#pragma unroll
        for (int nt = 0; nt < 4; ++nt)
          acc[mt][nt] = __builtin_amdgcn_mfma_f32_16x16x32_bf16(
              af[mt], bfr[nt], acc[mt][nt], 0, 0, 0);
    }
    __syncthreads();
  }

#pragma unroll
  for (int nt = 0; nt < 4; ++nt) {
    const int col = n0 + wc * 64 + nt * 16 + lm;
    const float bsv = bias[col];
    const int hh = col >> 6, dhh = col & 63;
#pragma unroll
    for (int mt = 0; mt < 4; ++mt) {
#pragma unroll
      for (int r = 0; r < 4; ++r) {
        const int row = m0 + wr * 64 + mt * 16 + lg * 4 + r;
        const int bb = row >> 11, ll = row & (L_ - 1);
        out[(((size_t)bb * H_ + hh) * L_ + ll) * DH_ + dhh] =
            f2bf((acc[mt][nt][r] + bsv) * oscale);
      }
    }
  }
}

// --------------------------------------------------------- flash attention fwd
// QBLK=128, KB=128 (one 128x128 tile per iteration -> prefetch latency fully
// hidden under compute, barrier drain ~free; per-iter overheads halved/score).
// Swapped QK^T and swapped PV (O^T = V^T P^T): q = lane lm -> softmax/alpha/1/l
// lane-local. T13 defer-max (skip O-rescale when max growth <= 8 in log2 dom).
// T5 setprio around MFMA clusters. Complement-paired qb decode: per-CU work
// exactly constant. LDS 64 KiB -> 2 blocks/CU.
__global__ __launch_bounds__(256) void attn_fwd(
    const u16* __restrict__ Q, const u16* __restrict__ K,
    const u16* __restrict__ V, float* __restrict__ out) {
  __shared__ u16 Ks[2][128 * 64];  // 32 KiB: K tiles, dbuf, row-swizzled cols
  __shared__ u16 Vt[64 * 128];     // 16 KiB: V^T (row dh, col k), swizzled
  __shared__ u16 Pl[4][16 * 128];  // 16 KiB: per-wave P[q][k], granule-swizzled

  // complement-paired decode: dispatch round r gets qb in {15-b, 8+b, 7-b, b}
  // -> every CU's 4 blocks sum to 30 q-tiles (perfect balance); longest first.
  const int bid = blockIdx.x;           // 1024 blocks
  const int rnd = bid >> 8, c = bid & 255;
  const int qbase = c >> 6;
  int qb;
  if      (rnd == 0) qb = 15 - qbase;
  else if (rnd == 1) qb = 8 + qbase;
  else if (rnd == 2) qb = 7 - qbase;
  else               qb = qbase;
  const int hid = c & 63;               // hid%8 == bid%8 -> head/XCD affinity
  const int h = hid & (H_ - 1), b = hid >> 4;

  const int tid = threadIdx.x, w = tid >> 6, lane = tid & 63;
  const int lm = lane & 15, lg = lane >> 4;
  const int lm7 = lm & 7;

  const size_t hb = (size_t)(b * H_ + h) * (L_ * DH_);
  const u16* Kh = K + hb;
  const u16* Vh = V + hb;

  // Q as B-fragments (col=q=lm, k=dh=lg*8+j); Q pre-scaled by 0.125*log2e
  bf16x8 qf00, qf01, qf10, qf11;
  {
    const int q0 = qb * 128 + w * 32 + lm;
    const u16* qp0 = Q + hb + (size_t)q0 * DH_ + lg * 8;
    qf00 = ld_g16(qp0);
    qf01 = ld_g16(qp0 + 32);
    const u16* qp1 = qp0 + 16 * DH_;
    qf10 = ld_g16(qp1);
    qf11 = ld_g16(qp1 + 32);
  }

  // ---- K staging: wave w covers rows w*32..w*32+31 (4 x gll16)
  const int srow = lane >> 3, sgp = lane & 7;
  auto stage_k = [&](int kb, int buf) {
#pragma unroll
    for (int i = 0; i < 4; ++i) {
      const int rb = w * 32 + i * 8;
      const int cg = (sgp ^ srow ^ ((rb >> 3) & 7)) * 8;   // inverse-swizzled src
      gll16(Kh + (size_t)(kb * 128 + rb + srow) * DH_ + cg, &Ks[buf][rb * 64]);
    }
  };

  // ---- V staging: thread loads 4 k-rows x 8 dh, transposes into Vt[dh][k]
  const int vkp = (tid >> 3) * 4;       // k base (0..124)
  const int vdb = (tid & 7) * 8;        // dh base
  uint4 vra, vrb, vrc, vrd;
  auto load_v = [&](int kb) {
    const u16* vp = Vh + (size_t)(kb * 128 + vkp) * DH_ + vdb;
    vra = *(const uint4*)vp;
    vrb = *(const uint4*)(vp + DH_);
    vrc = *(const uint4*)(vp + 2 * DH_);
    vrd = *(const uint4*)(vp + 3 * DH_);
  };
  auto write_vt = [&]() {
    const u16* p0 = (const u16*)&vra;
    const u16* p1 = (const u16*)&vrb;
    const u16* p2 = (const u16*)&vrc;
    const u16* p3 = (const u16*)&vrd;
#pragma unroll
    for (int j = 0; j < 8; ++j) {       // row = vdb+j (dh); swz on k bits 3..5
      const int row = vdb + j;
      const int sx = (j ^ (tid & 7)) << 3;
      *(unsigned int*)&Vt[row * 128 + ((vkp)     ^ sx)] =
          (unsigned int)p0[j] | ((unsigned int)p1[j] << 16);
      *(unsigned int*)&Vt[row * 128 + ((vkp + 2) ^ sx)] =
          (unsigned int)p2[j] | ((unsigned int)p3[j] << 16);
    }
  };

  float m0r = -INFINITY, m1r = -INFINITY;   // running row max (exp2 domain)
  float l0r = 0.f, l1r = 0.f;               // running row sum
  f32x4 o0[4], o1[4];                       // O^T accum: row dh, col q=lm
#pragma unroll
  for (int td = 0; td < 4; ++td) { o0[td] = f32x4{0,0,0,0}; o1[td] = f32x4{0,0,0,0}; }

  const int nb = qb + 1;

  // ---- prologue: stage tile 0
  stage_k(0, 0);
  load_v(0);
  write_vt();
  __syncthreads();

  for (int kb = 0; kb < nb; ++kb) {
    const int cur = kb & 1;
    const bool more = (kb + 1) < nb;
    if (more) { stage_k(kb + 1, cur ^ 1); load_v(kb + 1); }  // prefetch early

    // S^T = K Q^T for both q-halves; K frags read once, 128 k per iter
    f32x4 s0[8], s1[8];
    __builtin_amdgcn_s_setprio(1);
#pragma unroll
    for (int tt = 0; tt < 8; ++tt) {
      const int r = tt * 16 + lm;
      const int sw8 = (r ^ (r >> 3)) & 7;
      U16x8 c0, c1;
      c0.u = *(const uint4*)&Ks[cur][r * 64 + ((lg ^ sw8) * 8)];
      c1.u = *(const uint4*)&Ks[cur][r * 64 + (((4 | lg) ^ sw8) * 8)];
      f32x4 a = f32x4{0, 0, 0, 0};
      a = __builtin_amdgcn_mfma_f32_16x16x32_bf16(c0.b, qf00, a, 0, 0, 0);
      a = __builtin_amdgcn_mfma_f32_16x16x32_bf16(c1.b, qf01, a, 0, 0, 0);
      s0[tt] = a;
      f32x4 a1 = f32x4{0, 0, 0, 0};
      a1 = __builtin_amdgcn_mfma_f32_16x16x32_bf16(c0.b, qf10, a1, 0, 0, 0);
      a1 = __builtin_amdgcn_mfma_f32_16x16x32_bf16(c1.b, qf11, a1, 0, 0, 0);
      s1[tt] = a1;
    }
    __builtin_amdgcn_s_setprio(0);

    if (kb == qb) {  // diagonal tile: causal mask (local indices within 128)
      const int wq0 = w * 32 + lm, wq1 = wq0 + 16;
#pragma unroll
      for (int tt = 0; tt < 8; ++tt)
#pragma unroll
        for (int r2 = 0; r2 < 4; ++r2) {
          const int kk = tt * 16 + lg * 4 + r2;
          if (kk > wq0) s0[tt][r2] = -INFINITY;
          if (kk > wq1) s1[tt][r2] = -INFINITY;
        }
    }

    // online softmax (exp2 domain): in-lane reduce + xor16/xor32
    float mx0 = s0[0][0], mx1 = s1[0][0];
#pragma unroll
    for (int tt = 0; tt < 8; ++tt)
#pragma unroll
      for (int r2 = 0; r2 < 4; ++r2) {
        mx0 = fmaxf(mx0, s0[tt][r2]);
        mx1 = fmaxf(mx1, s1[tt][r2]);
      }
    mx0 = fmaxf(mx0, __shfl_xor(mx0, 16));
    mx0 = fmaxf(mx0, __shfl_xor(mx0, 32));
    mx1 = fmaxf(mx1, __shfl_xor(mx1, 16));
    mx1 = fmaxf(mx1, __shfl_xor(mx1, 32));

    // T13 defer-max: keep old m when growth <= 8 (log2 dom; P bounded by 2^8)
    const bool d0 = __all(mx0 <= m0r + 8.0f);
    const bool d1 = __all(mx1 <= m1r + 8.0f);
    const float mn0 = d0 ? m0r : fmaxf(m0r, mx0);
    const float mn1 = d1 ? m1r : fmaxf(m1r, mx1);
    const float al0 = d0 ? 1.0f : __builtin_amdgcn_exp2f(m0r - mn0);
    const float al1 = d1 ? 1.0f : __builtin_amdgcn_exp2f(m1r - mn1);

    float rs0 = 0.f, rs1 = 0.f;
#pragma unroll
    for (int tt = 0; tt < 8; ++tt)
#pragma unroll
      for (int r2 = 0; r2 < 4; ++r2) {
        const float p0 = __builtin_amdgcn_exp2f(s0[tt][r2] - mn0);
        const float p1 = __builtin_amdgcn_exp2f(s1[tt][r2] - mn1);
        s0[tt][r2] = p0; rs0 += p0;
        s1[tt][r2] = p1; rs1 += p1;
      }
    rs0 += __shfl_xor(rs0, 16);
    rs0 += __shfl_xor(rs0, 32);
    rs1 += __shfl_xor(rs1, 16);
    rs1 += __shfl_xor(rs1, 32);
    m0r = mn0; l0r = l0r * al0 + rs0;
    m1r = mn1; l1r = l1r * al1 + rs1;

    // P -> Pl (16-row x 128-col buffer, TIME-SHARED by q-halves; same-wave
    // DS ordering enforces write->read->overwrite->read)
    bf16x8 pa0[4], pa1[4];
#pragma unroll
    for (int tt = 0; tt < 8; ++tt) {
      const int goff = (((2 * tt + (lg >> 1)) ^ lm7) * 8) + (lg & 1) * 4;
      uint2 pk; pk.x = pk2(s0[tt][0], s0[tt][1]); pk.y = pk2(s0[tt][2], s0[tt][3]);
      *(uint2*)&Pl[w][lm * 128 + goff] = pk;
    }
#pragma unroll
    for (int sl = 0; sl < 4; ++sl) {
      U16x8 cc; cc.u = *(const uint4*)&Pl[w][lm * 128 + (((sl * 4 + lg) ^ lm7) * 8)];
      pa0[sl] = cc.b;
    }
#pragma unroll
    for (int tt = 0; tt < 8; ++tt) {
      const int goff = (((2 * tt + (lg >> 1)) ^ lm7) * 8) + (lg & 1) * 4;
      uint2 pk; pk.x = pk2(s1[tt][0], s1[tt][1]); pk.y = pk2(s1[tt][2], s1[tt][3]);
      *(uint2*)&Pl[w][lm * 128 + goff] = pk;
    }
#pragma unroll
    for (int sl = 0; sl < 4; ++sl) {
      U16x8 cc; cc.u = *(const uint4*)&Pl[w][lm * 128 + (((sl * 4 + lg) ^ lm7) * 8)];
      pa1[sl] = cc.b;
    }

    // rescale O^T (lane-local alpha, skipped when deferred)
    if (!d0) {
#pragma unroll
      for (int td = 0; td < 4; ++td) o0[td] *= al0;
    }
    if (!d1) {
#pragma unroll
      for (int td = 0; td < 4; ++td) o1[td] *= al1;
    }

    // PV: O^T = V^T P^T; Vt frags read once, reused by both halves
    __builtin_amdgcn_s_setprio(1);
#pragma unroll
    for (int td = 0; td < 4; ++td) {
      const int vr = td * 16 + lm;
      const int sw8 = (vr ^ (vr >> 3)) & 7;
#pragma unroll
      for (int sl = 0; sl < 4; ++sl) {
        U16x8 cv;
        cv.u = *(const uint4*)&Vt[vr * 128 + (((sl * 4 + lg) ^ sw8) * 8)];
        o0[td] = __builtin_amdgcn_mfma_f32_16x16x32_bf16(cv.b, pa0[sl], o0[td], 0, 0, 0);
        o1[td] = __builtin_amdgcn_mfma_f32_16x16x32_bf16(cv.b, pa1[sl], o1[td], 0, 0, 0);
      }
    }
    __builtin_amdgcn_s_setprio(0);

    __syncthreads();                 // all reads of Ks[cur]/Vt done; gll16 drained
    if (more) { write_vt(); __syncthreads(); }  // install V(kb+1), make visible
  }

  // epilogue: lane-local 1/l; O^T -> out[q][dh] as coalesced f32x4 stores
  const float inv0 = 1.f / l0r, inv1 = 1.f / l1r;
  const size_t obase = (size_t)b * L_ * D_ + (size_t)h * DH_;
  const int q0 = qb * 128 + w * 32 + lm, q1 = q0 + 16;
#pragma unroll
  for (int td = 0; td < 4; ++td) {
    f32x4 v0 = o0[td] * inv0;
    f32x4 v1 = o1[td] * inv1;
    *(f32x4*)&out[obase + (size_t)q0 * D_ + td * 16 + lg * 4] = v0;
    *(f32x4*)&out[obase + (size_t)q1 * D_ + td * 16 + lg * 4] = v1;
  }
}

// -------------------------------------------------------------------- launcher
extern "C" void kernel_launch(void* const* d_in, const int* in_sizes, int n_in,
                              void* d_out, int out_size, void* d_ws, size_t ws_size,
                              hipStream_t stream) {
  const float* x  = (const float*)d_in[0];
  const float* Wq = (const float*)d_in[1];
  const float* bq = (const float*)d_in[2];
  const float* Wk = (const float*)d_in[3];
  const float* bk = (const float*)d_in[4];
  const float* Wv = (const float*)d_in[5];
  const float* bv = (const float*)d_in[6];
  // d_in[7] = atten_mask (causal triu) — implemented analytically.

  char* ws = (char*)d_ws;
  u16* xb = (u16*)ws;                                   // 16 MiB
  u16* Wt = (u16*)(ws + (size_t)16 * 1024 * 1024);      //  6 MiB (3x W^T)
  u16* Qb = (u16*)(ws + (size_t)22 * 1024 * 1024);      // 16 MiB [B,H,L,DH]
  u16* Kb = (u16*)(ws + (size_t)38 * 1024 * 1024);      // 16 MiB
  u16* Vb = (u16*)(ws + (size_t)54 * 1024 * 1024);      // 16 MiB -> 70 MiB total

  conv_x_kernel<<<(B_ * L_ * D_ / 4) / 256, 256, 0, stream>>>(x, xb);
  conv_wt_kernel<<<dim3(32, 32, 3), dim3(32, 8), 0, stream>>>(Wq, Wk, Wv, Wt);
  qkv_gemm<<<dim3(64, 8, 3), 256, 0, stream>>>(xb, Wt, bq, bk, bv, Qb, Kb, Vb);
  attn_fwd<<<(L_ / 128) * H_ * B_, 256, 0, stream>>>(Qb, Kb, Vb, (float*)d_out);
}

// Round 11
// 249.450 us; speedup vs baseline: 1.2051x; 1.2051x over previous
//
#include <hip/hip_runtime.h>
#include <hip/hip_bf16.h>

#define B_  4
#define L_  2048
#define D_  1024
#define H_  16
#define DH_ 64

typedef unsigned short u16;
typedef __bf16 bf16x8 __attribute__((ext_vector_type(8)));
typedef float  f32x4  __attribute__((ext_vector_type(4)));

union U16x8 { uint4 u; bf16x8 b; u16 s[8]; };

__device__ inline bf16x8 ld_g16(const u16* p) {
  U16x8 c; c.u = *(const uint4*)p; return c.b;
}

__device__ inline u16 f2bf(float f) {
  union { __bf16 h; u16 s; } c; c.h = (__bf16)f; return c.s;
}

__device__ inline unsigned int pk2(float a, float b) {
  return (unsigned int)f2bf(a) | ((unsigned int)f2bf(b) << 16);
}

// async global->LDS, 16B per lane; LDS dest is wave-uniform base (HW adds lane*16)
__device__ inline void gll16(const u16* g, u16* l) {
  __builtin_amdgcn_global_load_lds(
      (const __attribute__((address_space(1))) unsigned int*)g,
      (__attribute__((address_space(3))) unsigned int*)l,
      16, 0, 0);
}

// ---------------------------------------------------------------- conv x -> bf16
__global__ __launch_bounds__(256) void conv_x_kernel(const float* __restrict__ x,
                                                     u16* __restrict__ xb) {
  const int i = blockIdx.x * 256 + threadIdx.x;
  const float4 v = ((const float4*)x)[i];
  ushort4 o;
  o.x = f2bf(v.x); o.y = f2bf(v.y); o.z = f2bf(v.z); o.w = f2bf(v.w);
  ((ushort4*)xb)[i] = o;
}

// ------------------------------------------------- W -> W^T bf16 (LDS transpose)
__global__ __launch_bounds__(256) void conv_wt_kernel(const float* __restrict__ Wq,
                                                      const float* __restrict__ Wk,
                                                      const float* __restrict__ Wv,
                                                      u16* __restrict__ Wt) {
  __shared__ float tile[32][33];
  const int z = blockIdx.z;
  const float* W = (z == 0) ? Wq : ((z == 1) ? Wk : Wv);
  u16* o = Wt + (size_t)z * D_ * D_;
  const int n0 = blockIdx.x * 32, k0 = blockIdx.y * 32;
  const int tx = threadIdx.x, ty = threadIdx.y;  // 32 x 8
#pragma unroll
  for (int i = 0; i < 4; ++i)
    tile[ty + i * 8][tx] = W[(size_t)(k0 + ty + i * 8) * D_ + n0 + tx];
  __syncthreads();
#pragma unroll
  for (int i = 0; i < 4; ++i)
    o[(size_t)(n0 + ty + i * 8) * D_ + k0 + tx] = f2bf(tile[tx][ty + i * 8]);
}

// --------------------------------------------------------------- QKV projection
// C[8192,1024] = xb @ W (+bias), W given transposed (Wt[n][k]). 128x128 tile, BK=64.
// Output HEAD-MAJOR [B,H,L,DH]. Q is pre-scaled by 0.125*log2(e) (folded QK scale).
__global__ __launch_bounds__(256) void qkv_gemm(
    const u16* __restrict__ xb, const u16* __restrict__ Wt,
    const float* __restrict__ bq, const float* __restrict__ bk,
    const float* __restrict__ bv,
    u16* __restrict__ Qo, u16* __restrict__ Ko, u16* __restrict__ Vo) {
  __shared__ u16 As[128 * 64];
  __shared__ u16 Bs[128 * 64];

  const int z = blockIdx.z;
  const u16* W = Wt + (size_t)z * (D_ * D_);
  const float* bias = (z == 0) ? bq : ((z == 1) ? bk : bv);
  u16* out = (z == 0) ? Qo : ((z == 1) ? Ko : Vo);
  const float oscale = (z == 0) ? (0.125f * 1.44269504088896340736f) : 1.0f;

  const int tid = threadIdx.x;
  const int w = tid >> 6, lane = tid & 63;
  const int wr = w >> 1, wc = w & 1;
  const int m0 = blockIdx.x * 128, n0 = blockIdx.y * 128;

  const int srow = lane >> 3;              // 0..7 within the 8-row strip
  const int scg  = (lane & 7) ^ srow;      // pre-swizzled source col-group

  f32x4 acc[4][4];
#pragma unroll
  for (int i = 0; i < 4; ++i)
#pragma unroll
    for (int j = 0; j < 4; ++j) acc[i][j] = f32x4{0.f, 0.f, 0.f, 0.f};

  const int lm = lane & 15, lg = lane >> 4;

  for (int kk = 0; kk < D_ / 64; ++kk) {
    const int k0 = kk * 64;
#pragma unroll
    for (int i = 0; i < 4; ++i) {
      const int rbase = i * 32 + w * 8;
      gll16(xb + (size_t)(m0 + rbase + srow) * D_ + k0 + scg * 8, &As[rbase * 64]);
      gll16(W  + (size_t)(n0 + rbase + srow) * D_ + k0 + scg * 8, &Bs[rbase * 64]);
    }
    __syncthreads();

#pragma unroll
    for (int st = 0; st < 2; ++st) {
      bf16x8 af[4], bfr[4];
#pragma unroll
      for (int mt = 0; mt < 4; ++mt) {
        const int r = wr * 64 + mt * 16 + lm;
        const int cg = (st * 4 + lg) ^ (r & 7);
        U16x8 c; c.u = *(const uint4*)&As[r * 64 + cg * 8];
        af[mt] = c.b;
      }
#pragma unroll
      for (int nt = 0; nt < 4; ++nt) {
        const int r = wc * 64 + nt * 16 + lm;
        const int cg = (st * 4 + lg) ^ (r & 7);
        U16x8 c; c.u = *(const uint4*)&Bs[r * 64 + cg * 8];
        bfr[nt] = c.b;
      }
#pragma unroll
      for (int mt = 0; mt < 4; ++mt)
#pragma unroll
        for (int nt = 0; nt < 4; ++nt)
          acc[mt][nt] = __builtin_amdgcn_mfma_f32_16x16x32_bf16(
              af[mt], bfr[nt], acc[mt][nt], 0, 0, 0);
    }
    __syncthreads();
  }

#pragma unroll
  for (int nt = 0; nt < 4; ++nt) {
    const int col = n0 + wc * 64 + nt * 16 + lm;
    const float bsv = bias[col];
    const int hh = col >> 6, dhh = col & 63;
#pragma unroll
    for (int mt = 0; mt < 4; ++mt) {
#pragma unroll
      for (int r = 0; r < 4; ++r) {
        const int row = m0 + wr * 64 + mt * 16 + lg * 4 + r;
        const int bb = row >> 11, ll = row & (L_ - 1);
        out[(((size_t)bb * H_ + hh) * L_ + ll) * DH_ + dhh] =
            f2bf((acc[mt][nt][r] + bsv) * oscale);
      }
    }
  }
}

// --------------------------------------------------------- flash attention fwd
// QBLK=128 (4 waves x 32 q-rows, 2 q-halves per wave), KB=64, causal.
// [Round-9 base structure: measured 97us.] Swapped QK^T + swapped PV (O^T =
// V^T P^T): q = lane lm -> softmax/alpha/1/l lane-local; K/Vt frags read once
// per iter, reused by both q-halves; Pl 16-row time-shared. LDS 32 KiB.
// Adds vs R9: T13 defer-max, T5 setprio, complement-paired qb decode.
__global__ __launch_bounds__(256) void attn_fwd(
    const u16* __restrict__ Q, const u16* __restrict__ K,
    const u16* __restrict__ V, float* __restrict__ out) {
  __shared__ u16 Ks[2][64 * 64];   // 16 KiB: K tiles, double-buffered, swizzled
  __shared__ u16 Vt[64 * 64];      //  8 KiB: V^T tile, swizzled
  __shared__ u16 Pl[4][16 * 64];   //  8 KiB: per-wave P[q][k], granule-swizzled

  // complement-paired decode: dispatch round rnd gets qb in {15-b, 8+b, 7-b, b}
  // -> every CU's 4 blocks sum to 30 q-tiles (exact balance); longest first;
  // hid%8 == bid%8 -> head/XCD L2 affinity.
  const int bid = blockIdx.x;           // 1024 blocks
  const int rnd = bid >> 8, c = bid & 255;
  const int qbase = c >> 6;
  int qb;
  if      (rnd == 0) qb = 15 - qbase;
  else if (rnd == 1) qb = 8 + qbase;
  else if (rnd == 2) qb = 7 - qbase;
  else               qb = qbase;
  const int hid = c & 63;
  const int h = hid & (H_ - 1), b = hid >> 4;

  const int tid = threadIdx.x, w = tid >> 6, lane = tid & 63;
  const int lm = lane & 15, lg = lane >> 4;
  const int lm7 = lm & 7;

  const size_t hb = (size_t)(b * H_ + h) * (L_ * DH_);
  const u16* Kh = K + hb;
  const u16* Vh = V + hb;

  // Q as B-fragments (col=q=lm, k=dh=lg*8+j); Q pre-scaled by 0.125*log2e
  bf16x8 qf00, qf01, qf10, qf11;
  {
    const int q0 = qb * 128 + w * 32 + lm;
    const u16* qp0 = Q + hb + (size_t)q0 * DH_ + lg * 8;
    qf00 = ld_g16(qp0);
    qf01 = ld_g16(qp0 + 32);
    const u16* qp1 = qp0 + 16 * DH_;
    qf10 = ld_g16(qp1);
    qf11 = ld_g16(qp1 + 32);
  }

  // ---- staging helpers
  const int srow = lane >> 3, sgp = lane & 7;
  auto stage_k = [&](int kb, int buf) {
    const int c0 = (sgp ^ srow ^ ((w * 2 + 0) & 7)) * 8;   // inverse-swizzled src
    const int c1 = (sgp ^ srow ^ ((w * 2 + 1) & 7)) * 8;
    const u16* s0 = Kh + (size_t)(kb * 64 + w * 16 + srow) * DH_;
    gll16(s0 + c0,            &Ks[buf][(w * 16) * 64]);
    gll16(s0 + 8 * DH_ + c1,  &Ks[buf][(w * 16 + 8) * 64]);
  };

  const int vkp = (tid >> 3) * 2;       // k-pair this thread transposes
  const int vdb = (tid & 7) * 8;        // dh base
  uint4 vr0, vr1;
  auto load_v = [&](int kb) {
    const u16* vp = Vh + (size_t)(kb * 64 + vkp) * DH_ + vdb;
    vr0 = *(const uint4*)vp;
    vr1 = *(const uint4*)(vp + DH_);
  };
  auto write_vt = [&]() {
    const u16* s0 = (const u16*)&vr0;
    const u16* s1 = (const u16*)&vr1;
#pragma unroll
    for (int j = 0; j < 8; ++j) {       // row = vdb+j; swz8(row) = j ^ (tid&7)
      const int row = vdb + j;
      const int sw8 = j ^ (tid & 7);
      *(unsigned int*)&Vt[row * 64 + (vkp ^ (sw8 << 3))] =
          (unsigned int)s0[j] | ((unsigned int)s1[j] << 16);
    }
  };

  float m0r = -INFINITY, m1r = -INFINITY;   // running row max (exp2 domain)
  float l0r = 0.f, l1r = 0.f;               // running row sum
  f32x4 o0[4], o1[4];                       // O^T accum: row dh, col q=lm
#pragma unroll
  for (int td = 0; td < 4; ++td) { o0[td] = f32x4{0,0,0,0}; o1[td] = f32x4{0,0,0,0}; }

  const int nb = 2 * qb + 2;

  // ---- prologue: stage tile 0
  stage_k(0, 0);
  load_v(0);
  write_vt();
  __syncthreads();

  for (int kb = 0; kb < nb; ++kb) {
    const int cur = kb & 1;
    const bool more = (kb + 1) < nb;
    if (more) { stage_k(kb + 1, cur ^ 1); load_v(kb + 1); }  // prefetch early

    // skip fully-masked waves (k_min > wave's max q) — wave-uniform
    if ((kb - 2 * qb) * 64 <= w * 32 + 31) {
      // S^T = K Q^T for both q-halves; K frags read once
      f32x4 s0[4], s1[4];
      __builtin_amdgcn_s_setprio(1);
#pragma unroll
      for (int tt = 0; tt < 4; ++tt) {
        const int r = tt * 16 + lm;
        const int sw8 = (r ^ (r >> 3)) & 7;
        U16x8 c0, c1;
        c0.u = *(const uint4*)&Ks[cur][r * 64 + ((lg ^ sw8) * 8)];
        c1.u = *(const uint4*)&Ks[cur][r * 64 + (((4 | lg) ^ sw8) * 8)];
        f32x4 a = f32x4{0, 0, 0, 0};
        a = __builtin_amdgcn_mfma_f32_16x16x32_bf16(c0.b, qf00, a, 0, 0, 0);
        a = __builtin_amdgcn_mfma_f32_16x16x32_bf16(c1.b, qf01, a, 0, 0, 0);
        s0[tt] = a;
        f32x4 a1 = f32x4{0, 0, 0, 0};
        a1 = __builtin_amdgcn_mfma_f32_16x16x32_bf16(c0.b, qf10, a1, 0, 0, 0);
        a1 = __builtin_amdgcn_mfma_f32_16x16x32_bf16(c1.b, qf11, a1, 0, 0, 0);
        s1[tt] = a1;
      }
      __builtin_amdgcn_s_setprio(0);

      if (kb >= 2 * qb) {  // diagonal tiles: causal mask (local indices)
        const int koff = (kb - 2 * qb) * 64;
        const int wq0 = w * 32 + lm, wq1 = wq0 + 16;
#pragma unroll
        for (int tt = 0; tt < 4; ++tt)
#pragma unroll
          for (int r = 0; r < 4; ++r) {
            const int kk = koff + tt * 16 + lg * 4 + r;
            if (kk > wq0) s0[tt][r] = -INFINITY;
            if (kk > wq1) s1[tt][r] = -INFINITY;
          }
      }

      // online softmax (exp2 domain): in-lane reduce + xor16/xor32
      float mx0 = s0[0][0], mx1 = s1[0][0];
#pragma unroll
      for (int tt = 0; tt < 4; ++tt)
#pragma unroll
        for (int r = 0; r < 4; ++r) {
          mx0 = fmaxf(mx0, s0[tt][r]);
          mx1 = fmaxf(mx1, s1[tt][r]);
        }
      mx0 = fmaxf(mx0, __shfl_xor(mx0, 16));
      mx0 = fmaxf(mx0, __shfl_xor(mx0, 32));
      mx1 = fmaxf(mx1, __shfl_xor(mx1, 16));
      mx1 = fmaxf(mx1, __shfl_xor(mx1, 32));

      // T13 defer-max: keep old m when growth <= 8 (log2 dom; P bounded by 2^8)
      const bool d0 = __all(mx0 <= m0r + 8.0f);
      const bool d1 = __all(mx1 <= m1r + 8.0f);
      const float mn0 = d0 ? m0r : fmaxf(m0r, mx0);
      const float mn1 = d1 ? m1r : fmaxf(m1r, mx1);
      const float al0 = d0 ? 1.0f : __builtin_amdgcn_exp2f(m0r - mn0);
      const float al1 = d1 ? 1.0f : __builtin_amdgcn_exp2f(m1r - mn1);

      float rs0 = 0.f, rs1 = 0.f;
#pragma unroll
      for (int tt = 0; tt < 4; ++tt)
#pragma unroll
        for (int r = 0; r < 4; ++r) {
          const float p0 = __builtin_amdgcn_exp2f(s0[tt][r] - mn0);
          const float p1 = __builtin_amdgcn_exp2f(s1[tt][r] - mn1);
          s0[tt][r] = p0; rs0 += p0;
          s1[tt][r] = p1; rs1 += p1;
        }
      rs0 += __shfl_xor(rs0, 16);
      rs0 += __shfl_xor(rs0, 32);
      rs1 += __shfl_xor(rs1, 16);
      rs1 += __shfl_xor(rs1, 32);
      m0r = mn0; l0r = l0r * al0 + rs0;
      m1r = mn1; l1r = l1r * al1 + rs1;

      // P -> Pl (16-row buffer, TIME-SHARED by q-halves; same-wave DS ordering
      // + compiler alias analysis enforce write->read->overwrite->read order)
      bf16x8 pa00, pa01, pa10, pa11;
#pragma unroll
      for (int tt = 0; tt < 4; ++tt) {
        const int goff = (((2 * tt + (lg >> 1)) ^ lm7) * 8) + (lg & 1) * 4;
        uint2 pk0; pk0.x = pk2(s0[tt][0], s0[tt][1]); pk0.y = pk2(s0[tt][2], s0[tt][3]);
        *(uint2*)&Pl[w][lm * 64 + goff] = pk0;
      }
      {
        U16x8 c2;
        c2.u = *(const uint4*)&Pl[w][lm * 64 + ((lg ^ lm7) * 8)];       pa00 = c2.b;
        c2.u = *(const uint4*)&Pl[w][lm * 64 + (((4 | lg) ^ lm7) * 8)]; pa01 = c2.b;
      }
#pragma unroll
      for (int tt = 0; tt < 4; ++tt) {
        const int goff = (((2 * tt + (lg >> 1)) ^ lm7) * 8) + (lg & 1) * 4;
        uint2 pk1; pk1.x = pk2(s1[tt][0], s1[tt][1]); pk1.y = pk2(s1[tt][2], s1[tt][3]);
        *(uint2*)&Pl[w][lm * 64 + goff] = pk1;
      }
      {
        U16x8 c2;
        c2.u = *(const uint4*)&Pl[w][lm * 64 + ((lg ^ lm7) * 8)];       pa10 = c2.b;
        c2.u = *(const uint4*)&Pl[w][lm * 64 + (((4 | lg) ^ lm7) * 8)]; pa11 = c2.b;
      }

      // rescale O^T (lane-local alpha; skipped entirely when deferred)
      if (!d0) {
#pragma unroll
        for (int td = 0; td < 4; ++td) o0[td] *= al0;
      }
      if (!d1) {
#pragma unroll
        for (int td = 0; td < 4; ++td) o1[td] *= al1;
      }

      // PV: O^T = V^T P^T; Vt frags read once, reused by both halves
      __builtin_amdgcn_s_setprio(1);
#pragma unroll
      for (int td = 0; td < 4; ++td) {
        const int vr = td * 16 + lm;
        const int sw8 = (vr ^ (vr >> 3)) & 7;
        U16x8 c0, c1;
        c0.u = *(const uint4*)&Vt[vr * 64 + ((lg ^ sw8) * 8)];
        c1.u = *(const uint4*)&Vt[vr * 64 + (((4 | lg) ^ sw8) * 8)];
        o0[td] = __builtin_amdgcn_mfma_f32_16x16x32_bf16(c0.b, pa00, o0[td], 0, 0, 0);
        o0[td] = __builtin_amdgcn_mfma_f32_16x16x32_bf16(c1.b, pa01, o0[td], 0, 0, 0);
        o1[td] = __builtin_amdgcn_mfma_f32_16x16x32_bf16(c0.b, pa10, o1[td], 0, 0, 0);
        o1[td] = __builtin_amdgcn_mfma_f32_16x16x32_bf16(c1.b, pa11, o1[td], 0, 0, 0);
      }
      __builtin_amdgcn_s_setprio(0);
    }

    __syncthreads();                 // all reads of Ks[cur]/Vt done; gll16 drained
    if (more) { write_vt(); __syncthreads(); }  // install V(kb+1), make visible
  }

  // epilogue: lane-local 1/l; O^T -> out[q][dh] as coalesced f32x4 stores
  const float inv0 = 1.f / l0r, inv1 = 1.f / l1r;
  const size_t obase = (size_t)b * L_ * D_ + (size_t)h * DH_;
  const int q0 = qb * 128 + w * 32 + lm, q1 = q0 + 16;
#pragma unroll
  for (int td = 0; td < 4; ++td) {
    f32x4 v0 = o0[td] * inv0;
    f32x4 v1 = o1[td] * inv1;
    *(f32x4*)&out[obase + (size_t)q0 * D_ + td * 16 + lg * 4] = v0;
    *(f32x4*)&out[obase + (size_t)q1 * D_ + td * 16 + lg * 4] = v1;
  }
}

// -------------------------------------------------------------------- launcher
extern "C" void kernel_launch(void* const* d_in, const int* in_sizes, int n_in,
                              void* d_out, int out_size, void* d_ws, size_t ws_size,
                              hipStream_t stream) {
  const float* x  = (const float*)d_in[0];
  const float* Wq = (const float*)d_in[1];
  const float* bq = (const float*)d_in[2];
  const float* Wk = (const float*)d_in[3];
  const float* bk = (const float*)d_in[4];
  const float* Wv = (const float*)d_in[5];
  const float* bv = (const float*)d_in[6];
  // d_in[7] = atten_mask (causal triu) — implemented analytically.

  char* ws = (char*)d_ws;
  u16* xb = (u16*)ws;                                   // 16 MiB
  u16* Wt = (u16*)(ws + (size_t)16 * 1024 * 1024);      //  6 MiB (3x W^T)
  u16* Qb = (u16*)(ws + (size_t)22 * 1024 * 1024);      // 16 MiB [B,H,L,DH]
  u16* Kb = (u16*)(ws + (size_t)38 * 1024 * 1024);      // 16 MiB
  u16* Vb = (u16*)(ws + (size_t)54 * 1024 * 1024);      // 16 MiB -> 70 MiB total

  conv_x_kernel<<<(B_ * L_ * D_ / 4) / 256, 256, 0, stream>>>(x, xb);
  conv_wt_kernel<<<dim3(32, 32, 3), dim3(32, 8), 0, stream>>>(Wq, Wk, Wv, Wt);
  qkv_gemm<<<dim3(64, 8, 3), 256, 0, stream>>>(xb, Wt, bq, bk, bv, Qb, Kb, Vb);
  attn_fwd<<<(L_ / 128) * H_ * B_, 256, 0, stream>>>(Qb, Kb, Vb, (float*)d_out);
}